// Round 7
// baseline (252.042 us; speedup 1.0000x reference)
//
#include <hip/hip_runtime.h>
#include <hip/hip_bf16.h>
#include <math.h>

#define N_Q   512
#define M_ALL 2048
#define CHN   256
#define TOPK  6
#define INV_C (1.0f / 256.0f)

// ws[0] = loss accumulator (float), ws[1] = done-counter (uint bits)
#define WS_LOGIT 4096   // [N_Q][M_ALL]  (n-major)

// =============== kernel 1: fused bias + GEMM ===============
// logits[n][m] = bias[m] - 2 * sum_c (w~_c * a_mc) * b_nc
#define BM 64
#define BN 32
#define KC 64
#define LDA (BM + 4)
#define LDB (BN + 4)

__global__ __launch_bounds__(256) void gcn_gemm(
    const float* __restrict__ micro_all,  // A [M, C]
    const float* __restrict__ micro,      // B [N, C]
    const float* __restrict__ fc_w,
    float* __restrict__ logits,           // [N_Q][M_ALL]
    float* __restrict__ loss_accum,       // ws[0]
    unsigned int* __restrict__ done_cnt)  // ws[1]
{
    __shared__ float As[KC][LDA];
    __shared__ float Bs[KC][LDB];
    __shared__ float s_w[CHN];
    __shared__ float s_bias[BM];

    const int t  = threadIdx.x;
    const int m0 = blockIdx.x * BM;
    const int n0 = blockIdx.y * BN;
    const int tm = t & 15;
    const int tn = t >> 4;

    if (blockIdx.x == 0 && blockIdx.y == 0 && t == 0) {
        *loss_accum = 0.0f;
        *done_cnt   = 0u;
    }

    s_w[t] = fc_w[t] - INV_C;
    __syncthreads();

    float acc00 = 0.f, acc01 = 0.f, acc10 = 0.f, acc11 = 0.f;
    float acc20 = 0.f, acc21 = 0.f, acc30 = 0.f, acc31 = 0.f;
    float biasAcc[4] = {0.f, 0.f, 0.f, 0.f};

    for (int kc0 = 0; kc0 < CHN; kc0 += KC) {
        #pragma unroll
        for (int i = 0; i < 4; ++i) {
            const int item = t + i * 256;
            const int r = item >> 4, c4 = item & 15;
            float4 v = *(const float4*)(micro_all + (size_t)(m0 + r) * CHN + kc0 + c4 * 4);
            const float sx = v.x * s_w[kc0 + c4 * 4 + 0];
            const float sy = v.y * s_w[kc0 + c4 * 4 + 1];
            const float sz = v.z * s_w[kc0 + c4 * 4 + 2];
            const float sw = v.w * s_w[kc0 + c4 * 4 + 3];
            As[c4 * 4 + 0][r] = sx;
            As[c4 * 4 + 1][r] = sy;
            As[c4 * 4 + 2][r] = sz;
            As[c4 * 4 + 3][r] = sw;
            float p = v.x * sx + v.y * sy + v.z * sz + v.w * sw;
            #pragma unroll
            for (int mask = 8; mask >= 1; mask >>= 1)
                p += __shfl_xor(p, mask, 16);
            biasAcc[i] += p;
        }
        #pragma unroll
        for (int i = 0; i < 2; ++i) {
            const int item = t + i * 256;
            const int r = item >> 4, c4 = item & 15;
            float4 v = *(const float4*)(micro + (size_t)(n0 + r) * CHN + kc0 + c4 * 4);
            Bs[c4 * 4 + 0][r] = v.x;
            Bs[c4 * 4 + 1][r] = v.y;
            Bs[c4 * 4 + 2][r] = v.z;
            Bs[c4 * 4 + 3][r] = v.w;
        }
        __syncthreads();

        #pragma unroll 16
        for (int k = 0; k < KC; ++k) {
            const float4 a = *(const float4*)&As[k][tm * 4];
            const float2 b = *(const float2*)&Bs[k][tn * 2];
            acc00 += a.x * b.x; acc01 += a.x * b.y;
            acc10 += a.y * b.x; acc11 += a.y * b.y;
            acc20 += a.z * b.x; acc21 += a.z * b.y;
            acc30 += a.w * b.x; acc31 += a.w * b.y;
        }
        __syncthreads();
    }

    if ((t & 15) == 0) {
        #pragma unroll
        for (int i = 0; i < 4; ++i)
            s_bias[i * 16 + (t >> 4)] = biasAcc[i];
    }
    __syncthreads();

    const float4 bi = *(const float4*)&s_bias[tm * 4];
    {
        const int n = n0 + tn * 2;
        float4 o;
        o.x = bi.x - 2.f * acc00;
        o.y = bi.y - 2.f * acc10;
        o.z = bi.z - 2.f * acc20;
        o.w = bi.w - 2.f * acc30;
        *(float4*)&logits[(size_t)n * M_ALL + m0 + tm * 4] = o;
    }
    {
        const int n = n0 + tn * 2 + 1;
        float4 o;
        o.x = bi.x - 2.f * acc01;
        o.y = bi.y - 2.f * acc11;
        o.z = bi.z - 2.f * acc21;
        o.w = bi.w - 2.f * acc31;
        *(float4*)&logits[(size_t)n * M_ALL + m0 + tm * 4] = o;
    }
}

// =============== kernel 2: top-6 + softmax + epilogue + fused finalize ===============
#define BLOCK 256
#define WAVES (BLOCK / 64)
#define MPT   (M_ALL / BLOCK)
#define NCAND (WAVES * TOPK)

__global__ __launch_bounds__(BLOCK) void gcn_topk(
    const float* __restrict__ logits,
    const float* __restrict__ micro,
    const float* __restrict__ label,
    const float* __restrict__ micro_all,
    const float* __restrict__ label_all,
    float* __restrict__ out,
    float* __restrict__ loss_accum,
    unsigned int* __restrict__ done_cnt)
{
    __shared__ float s_cv[NCAND];
    __shared__ int   s_ci[NCAND];

    const int n    = blockIdx.x;
    const int t    = threadIdx.x;
    const int wave = t >> 6;
    const int lane = t & 63;

    float logit[MPT];
    #pragma unroll
    for (int j = 0; j < MPT; ++j)
        logit[j] = logits[(size_t)n * M_ALL + t + j * BLOCK];

    unsigned taken = 0u;
    float wv[TOPK];
    int   wi[TOPK];
    #pragma unroll
    for (int k = 0; k < TOPK; ++k) {
        float best  = -INFINITY;
        int   bestj = -1;
        #pragma unroll
        for (int j = 0; j < MPT; ++j) {
            bool avail = ((taken >> j) & 1u) == 0u;
            if (avail && logit[j] > best) { best = logit[j]; bestj = j; }
        }
        float v  = best;
        int   mi = (bestj < 0) ? -1 : (t + bestj * BLOCK);
        #pragma unroll
        for (int mask = 32; mask > 0; mask >>= 1) {
            float ov = __shfl_xor(v,  mask, 64);
            int   om = __shfl_xor(mi, mask, 64);
            if (ov > v) { v = ov; mi = om; }
        }
        wv[k] = v;
        wi[k] = mi;
        if (mi >= 0 && t == (mi & (BLOCK - 1))) taken |= 1u << (mi >> 8);
    }
    if (lane == 0) {
        #pragma unroll
        for (int k = 0; k < TOPK; ++k) {
            s_cv[wave * TOPK + k] = wv[k];
            s_ci[wave * TOPK + k] = wi[k];
        }
    }
    __syncthreads();

    float top_val[TOPK];
    int   top_idx[TOPK];
    unsigned ctk = 0u;
    #pragma unroll
    for (int k = 0; k < TOPK; ++k) {
        float best = -INFINITY;
        int   bi   = 0;
        #pragma unroll
        for (int c = 0; c < NCAND; ++c) {
            bool avail = ((ctk >> c) & 1u) == 0u;
            float cv = s_cv[c];
            if (avail && cv > best) { best = cv; bi = c; }
        }
        top_val[k] = best;
        top_idx[k] = s_ci[bi];
        ctk |= 1u << bi;
    }

    const float mx = top_val[0];
    float e[TOPK];
    float esum = 0.0f;
    #pragma unroll
    for (int k = 0; k < TOPK; ++k) { e[k] = __expf(top_val[k] - mx); esum += e[k]; }
    const float inv = 1.0f / esum;

    float outv = micro[(size_t)n * CHN + t];
    #pragma unroll
    for (int k = 0; k < TOPK; ++k)
        outv += (e[k] * inv) * micro_all[(size_t)top_idx[k] * CHN + t];
    out[n * CHN + t] = outv;

    if (t == 0) {
        const float lab = label[n];
        float l = 0.0f;
        #pragma unroll
        for (int k = 0; k < TOPK; ++k)
            l += (e[k] * inv) * fabsf(label_all[top_idx[k]] - lab);
        atomicAdd(loss_accum, l);
        __threadfence();
        const unsigned old = atomicAdd(done_cnt, 1u);
        if (old == N_Q - 1) {
            const float total = atomicAdd(loss_accum, 0.0f);
            out[N_Q * CHN] = 1e-4f + total / (float)N_Q;
        }
    }
}

extern "C" void kernel_launch(void* const* d_in, const int* in_sizes, int n_in,
                              void* d_out, int out_size, void* d_ws, size_t ws_size,
                              hipStream_t stream) {
    const float* micro     = (const float*)d_in[0];
    const float* label     = (const float*)d_in[1];
    const float* micro_all = (const float*)d_in[2];
    const float* label_all = (const float*)d_in[3];
    const float* fc_w      = (const float*)d_in[4];
    float* out  = (float*)d_out;
    float* ws   = (float*)d_ws;
    float*        loss    = ws;
    unsigned int* counter = (unsigned int*)(ws + 1);
    float*        logits  = ws + WS_LOGIT;

    // MEASUREMENT ROUND: launch gemm 8x (idempotent) to expose t_gemm via
    // total-duration delta vs round 5:  t_gemm = (total6 - total5) / 7.
    for (int rep = 0; rep < 8; ++rep) {
        gcn_gemm<<<dim3(M_ALL / BM, N_Q / BN), 256, 0, stream>>>(
            micro_all, micro, fc_w, logits, loss, counter);
    }
    gcn_topk<<<N_Q, BLOCK, 0, stream>>>(logits, micro, label, micro_all,
                                        label_all, out, loss, counter);
}

// Round 9
// 96.136 us; speedup vs baseline: 2.6217x; 2.6217x over previous
//
#include <hip/hip_runtime.h>
#include <hip/hip_bf16.h>
#include <math.h>

#define N_Q   512
#define M_ALL 2048
#define CHN   256
#define TOPK  6
#define INV_C (1.0f / 256.0f)

// ws layout (float offsets): [64..576) per-n loss, [4096..) logits [N][M]
#define WS_LOSS  64
#define WS_LOGIT 4096

// =============== kernel 1: fused bias + fp32 GEMM ===============
// logits[n][m] = bias[m] - 2 * sum_c (w~_c * a_mc) * b_nc
#define BM 64
#define BN 32
#define KC 64
#define LDA (BM + 4)
#define LDB (BN + 4)

__global__ __launch_bounds__(256) void gcn_gemm(
    const float* __restrict__ micro_all,  // A [M, C]
    const float* __restrict__ micro,      // B [N, C]
    const float* __restrict__ fc_w,
    float* __restrict__ logits)           // [N_Q][M_ALL]
{
    __shared__ float As[KC][LDA];
    __shared__ float Bs[KC][LDB];
    __shared__ float s_w[CHN];
    __shared__ float s_bias[BM];

    const int t  = threadIdx.x;
    const int m0 = blockIdx.x * BM;
    const int n0 = blockIdx.y * BN;
    const int tm = t & 15;
    const int tn = t >> 4;

    s_w[t] = fc_w[t] - INV_C;
    __syncthreads();

    float acc00 = 0.f, acc01 = 0.f, acc10 = 0.f, acc11 = 0.f;
    float acc20 = 0.f, acc21 = 0.f, acc30 = 0.f, acc31 = 0.f;
    float biasAcc[4] = {0.f, 0.f, 0.f, 0.f};

    for (int kc0 = 0; kc0 < CHN; kc0 += KC) {
        #pragma unroll
        for (int i = 0; i < 4; ++i) {
            const int item = t + i * 256;
            const int r = item >> 4, c4 = item & 15;
            float4 v = *(const float4*)(micro_all + (size_t)(m0 + r) * CHN + kc0 + c4 * 4);
            const float sx = v.x * s_w[kc0 + c4 * 4 + 0];
            const float sy = v.y * s_w[kc0 + c4 * 4 + 1];
            const float sz = v.z * s_w[kc0 + c4 * 4 + 2];
            const float sw = v.w * s_w[kc0 + c4 * 4 + 3];
            As[c4 * 4 + 0][r] = sx;
            As[c4 * 4 + 1][r] = sy;
            As[c4 * 4 + 2][r] = sz;
            As[c4 * 4 + 3][r] = sw;
            float p = v.x * sx + v.y * sy + v.z * sz + v.w * sw;
            #pragma unroll
            for (int mask = 8; mask >= 1; mask >>= 1)
                p += __shfl_xor(p, mask, 16);
            biasAcc[i] += p;
        }
        #pragma unroll
        for (int i = 0; i < 2; ++i) {
            const int item = t + i * 256;
            const int r = item >> 4, c4 = item & 15;
            float4 v = *(const float4*)(micro + (size_t)(n0 + r) * CHN + kc0 + c4 * 4);
            Bs[c4 * 4 + 0][r] = v.x;
            Bs[c4 * 4 + 1][r] = v.y;
            Bs[c4 * 4 + 2][r] = v.z;
            Bs[c4 * 4 + 3][r] = v.w;
        }
        __syncthreads();

        #pragma unroll 16
        for (int k = 0; k < KC; ++k) {
            const float4 a = *(const float4*)&As[k][tm * 4];
            const float2 b = *(const float2*)&Bs[k][tn * 2];
            acc00 += a.x * b.x; acc01 += a.x * b.y;
            acc10 += a.y * b.x; acc11 += a.y * b.y;
            acc20 += a.z * b.x; acc21 += a.z * b.y;
            acc30 += a.w * b.x; acc31 += a.w * b.y;
        }
        __syncthreads();
    }

    if ((t & 15) == 0) {
        #pragma unroll
        for (int i = 0; i < 4; ++i)
            s_bias[i * 16 + (t >> 4)] = biasAcc[i];
    }
    __syncthreads();

    const float4 bi = *(const float4*)&s_bias[tm * 4];
    {
        const int n = n0 + tn * 2;
        float4 o;
        o.x = bi.x - 2.f * acc00;
        o.y = bi.y - 2.f * acc10;
        o.z = bi.z - 2.f * acc20;
        o.w = bi.w - 2.f * acc30;
        *(float4*)&logits[(size_t)n * M_ALL + m0 + tm * 4] = o;
    }
    {
        const int n = n0 + tn * 2 + 1;
        float4 o;
        o.x = bi.x - 2.f * acc01;
        o.y = bi.y - 2.f * acc11;
        o.z = bi.z - 2.f * acc21;
        o.w = bi.w - 2.f * acc31;
        *(float4*)&logits[(size_t)n * M_ALL + m0 + tm * 4] = o;
    }
}

// =============== kernel 2: top-6 + softmax + epilogue (NO atomics) ===============
#define BLOCK 256
#define WAVES (BLOCK / 64)
#define MPT   (M_ALL / BLOCK)
#define NCAND (WAVES * TOPK)

__global__ __launch_bounds__(BLOCK) void gcn_topk(
    const float* __restrict__ logits,
    const float* __restrict__ micro,
    const float* __restrict__ label,
    const float* __restrict__ micro_all,
    const float* __restrict__ label_all,
    float* __restrict__ out,
    float* __restrict__ loss_arr)        // [N_Q] per-n loss, plain stores
{
    __shared__ float s_cv[NCAND];
    __shared__ int   s_ci[NCAND];

    const int n    = blockIdx.x;
    const int t    = threadIdx.x;
    const int wave = t >> 6;
    const int lane = t & 63;

    float logit[MPT];
    #pragma unroll
    for (int j = 0; j < MPT; ++j)
        logit[j] = logits[(size_t)n * M_ALL + t + j * BLOCK];

    unsigned taken = 0u;
    float wv[TOPK];
    int   wi[TOPK];
    #pragma unroll
    for (int k = 0; k < TOPK; ++k) {
        float best  = -INFINITY;
        int   bestj = -1;
        #pragma unroll
        for (int j = 0; j < MPT; ++j) {
            bool avail = ((taken >> j) & 1u) == 0u;
            if (avail && logit[j] > best) { best = logit[j]; bestj = j; }
        }
        float v  = best;
        int   mi = (bestj < 0) ? -1 : (t + bestj * BLOCK);
        #pragma unroll
        for (int mask = 32; mask > 0; mask >>= 1) {
            float ov = __shfl_xor(v,  mask, 64);
            int   om = __shfl_xor(mi, mask, 64);
            if (ov > v) { v = ov; mi = om; }
        }
        wv[k] = v;
        wi[k] = mi;
        if (mi >= 0 && t == (mi & (BLOCK - 1))) taken |= 1u << (mi >> 8);
    }
    if (lane == 0) {
        #pragma unroll
        for (int k = 0; k < TOPK; ++k) {
            s_cv[wave * TOPK + k] = wv[k];
            s_ci[wave * TOPK + k] = wi[k];
        }
    }
    __syncthreads();

    float top_val[TOPK];
    int   top_idx[TOPK];
    unsigned ctk = 0u;
    #pragma unroll
    for (int k = 0; k < TOPK; ++k) {
        float best = -INFINITY;
        int   bi   = 0;
        #pragma unroll
        for (int c = 0; c < NCAND; ++c) {
            bool avail = ((ctk >> c) & 1u) == 0u;
            float cv = s_cv[c];
            if (avail && cv > best) { best = cv; bi = c; }
        }
        top_val[k] = best;
        top_idx[k] = s_ci[bi];
        ctk |= 1u << bi;
    }

    const float mx = top_val[0];
    float e[TOPK];
    float esum = 0.0f;
    #pragma unroll
    for (int k = 0; k < TOPK; ++k) { e[k] = __expf(top_val[k] - mx); esum += e[k]; }
    const float inv = 1.0f / esum;

    float outv = micro[(size_t)n * CHN + t];
    #pragma unroll
    for (int k = 0; k < TOPK; ++k)
        outv += (e[k] * inv) * micro_all[(size_t)top_idx[k] * CHN + t];
    out[n * CHN + t] = outv;

    if (t == 0) {
        const float lab = label[n];
        float l = 0.0f;
        #pragma unroll
        for (int k = 0; k < TOPK; ++k)
            l += (e[k] * inv) * fabsf(label_all[top_idx[k]] - lab);
        loss_arr[n] = l;          // plain store — no atomic, no fence
    }
}

// =============== kernel 3: reduce 512 per-n losses ===============
__global__ __launch_bounds__(256) void gcn_finalize(
    const float* __restrict__ loss_arr,
    float* __restrict__ out)
{
    __shared__ float red[4];
    const int t = threadIdx.x;
    float v = loss_arr[t] + loss_arr[t + 256];
    #pragma unroll
    for (int mask = 32; mask >= 1; mask >>= 1)
        v += __shfl_xor(v, mask, 64);
    if ((t & 63) == 0) red[t >> 6] = v;
    __syncthreads();
    if (t == 0)
        out[N_Q * CHN] = 1e-4f + (red[0] + red[1] + red[2] + red[3]) / (float)N_Q;
}

extern "C" void kernel_launch(void* const* d_in, const int* in_sizes, int n_in,
                              void* d_out, int out_size, void* d_ws, size_t ws_size,
                              hipStream_t stream) {
    const float* micro     = (const float*)d_in[0];
    const float* label     = (const float*)d_in[1];
    const float* micro_all = (const float*)d_in[2];
    const float* label_all = (const float*)d_in[3];
    const float* fc_w      = (const float*)d_in[4];
    float* out    = (float*)d_out;
    float* ws     = (float*)d_ws;
    float* loss   = ws + WS_LOSS;
    float* logits = ws + WS_LOGIT;

    gcn_gemm<<<dim3(M_ALL / BM, N_Q / BN), 256, 0, stream>>>(
        micro_all, micro, fc_w, logits);
    gcn_topk<<<N_Q, BLOCK, 0, stream>>>(logits, micro, label, micro_all,
                                        label_all, out, loss);
    gcn_finalize<<<1, 256, 0, stream>>>(loss, out);
}

// Round 10
// 87.451 us; speedup vs baseline: 2.8821x; 1.0993x over previous
//
#include <hip/hip_runtime.h>
#include <hip/hip_bf16.h>
#include <math.h>

#define N_Q   512
#define M_ALL 2048
#define CHN   256
#define TOPK  6
#define INV_C (1.0f / 256.0f)

// ws layout (float offsets): [64..576) per-n loss, [4096..) logits [N][M]
#define WS_LOSS  64
#define WS_LOGIT 4096

typedef __bf16 bf16x8 __attribute__((ext_vector_type(8)));
typedef float  f32x4  __attribute__((ext_vector_type(4)));

static __device__ __forceinline__ unsigned short bfbits(float x) {
    __bf16 h = (__bf16)x;
    unsigned short u;
    __builtin_memcpy(&u, &h, 2);
    return u;
}

// =============== kernel 1: fused bias + MFMA-bf16 GEMM (approx logits) ===============
// logits[n][m] ~= bias[m] - 2 * sum_c (w~_c a_mc) b_nc, computed in bf16 MFMA.
// Only used to NOMINATE top candidates; exact fp32 recompute happens in topk.
#define BM 64
#define BN 32
#define LDK 264   // 256 + 8 bf16 pad

__global__ __launch_bounds__(256) void gcn_gemm(
    const float* __restrict__ micro_all,  // A [M, C]
    const float* __restrict__ micro,      // B [N, C]
    const float* __restrict__ fc_w,
    float* __restrict__ logits)           // [N_Q][M_ALL]
{
    __shared__ unsigned short sA[BM][LDK];  // bf16 bits of w~*micro_all, [m][k]
    __shared__ unsigned short sB[BN][LDK];  // bf16 bits of micro,        [n][k]
    __shared__ float s_bias[BM];

    const int t    = threadIdx.x;
    const int w    = t >> 6;
    const int l15  = t & 15;
    const int quad = (t >> 4) & 3;
    const int m0   = blockIdx.x * BM;
    const int n0   = blockIdx.y * BN;

    // staging layout: 16 threads per row; thread handles channels
    // c = (t&15)*4 + cc*64, cc=0..3  (each instruction reads 256B-contiguous segs)
    const int rg = t >> 4;          // row-group 0..15
    const int c0 = (t & 15) * 4;    // channel base

    float4 wv[4];
    #pragma unroll
    for (int cc = 0; cc < 4; ++cc) {
        float4 x = *(const float4*)(fc_w + c0 + cc * 64);
        x.x -= INV_C; x.y -= INV_C; x.z -= INV_C; x.w -= INV_C;
        wv[cc] = x;
    }

    // ---- stage A (w~ * micro_all) as bf16 [m][k], fp32 bias along the way ----
    #pragma unroll
    for (int i = 0; i < 4; ++i) {
        const int r = i * 16 + rg;
        const float* rp = micro_all + (size_t)(m0 + r) * CHN;
        float p = 0.0f;
        #pragma unroll
        for (int cc = 0; cc < 4; ++cc) {
            const float4 v = *(const float4*)(rp + c0 + cc * 64);
            const float sx = v.x * wv[cc].x;
            const float sy = v.y * wv[cc].y;
            const float sz = v.z * wv[cc].z;
            const float sw = v.w * wv[cc].w;
            ushort4 pk;
            pk.x = bfbits(sx); pk.y = bfbits(sy); pk.z = bfbits(sz); pk.w = bfbits(sw);
            *(ushort4*)&sA[r][c0 + cc * 64] = pk;
            p += v.x * sx + v.y * sy + v.z * sz + v.w * sw;
        }
        #pragma unroll
        for (int mask = 8; mask >= 1; mask >>= 1)
            p += __shfl_xor(p, mask, 64);   // reduce over the 16-lane row group
        if ((t & 15) == 0) s_bias[r] = p;
    }

    // ---- stage B (micro) as bf16 [n][k] ----
    #pragma unroll
    for (int i = 0; i < 2; ++i) {
        const int r = i * 16 + rg;
        const float* rp = micro + (size_t)(n0 + r) * CHN;
        #pragma unroll
        for (int cc = 0; cc < 4; ++cc) {
            const float4 v = *(const float4*)(rp + c0 + cc * 64);
            ushort4 pk;
            pk.x = bfbits(v.x); pk.y = bfbits(v.y); pk.z = bfbits(v.z); pk.w = bfbits(v.w);
            *(ushort4*)&sB[r][c0 + cc * 64] = pk;
        }
    }
    __syncthreads();

    // ---- MFMA: wave w -> nt=w&1 (16 n), mtp=w>>1 (32 m as 2x16) ----
    const int nt    = w & 1;
    const int mtp   = w >> 1;
    const int rowB  = nt * 16 + l15;
    const int rowA0 = mtp * 32 + l15;
    const int rowA1 = mtp * 32 + 16 + l15;

    f32x4 acc0 = {0.f, 0.f, 0.f, 0.f};
    f32x4 acc1 = {0.f, 0.f, 0.f, 0.f};
    #pragma unroll
    for (int ks = 0; ks < 8; ++ks) {
        const int k0 = ks * 32 + quad * 8;
        const bf16x8 a  = *(const bf16x8*)&sB[rowB][k0];
        const bf16x8 b0 = *(const bf16x8*)&sA[rowA0][k0];
        const bf16x8 b1 = *(const bf16x8*)&sA[rowA1][k0];
        acc0 = __builtin_amdgcn_mfma_f32_16x16x32_bf16(a, b0, acc0, 0, 0, 0);
        acc1 = __builtin_amdgcn_mfma_f32_16x16x32_bf16(a, b1, acc1, 0, 0, 0);
    }

    // ---- epilogue: logit = bias[m] - 2*dot ; D: col(l15)=m, row(quad*4+reg)=n ----
    const float bias0 = s_bias[mtp * 32 + l15];
    const float bias1 = s_bias[mtp * 32 + 16 + l15];
    #pragma unroll
    for (int reg = 0; reg < 4; ++reg) {
        const int n = n0 + nt * 16 + quad * 4 + reg;
        logits[(size_t)n * M_ALL + m0 + mtp * 32 + l15]      = bias0 - 2.f * acc0[reg];
        logits[(size_t)n * M_ALL + m0 + mtp * 32 + 16 + l15] = bias1 - 2.f * acc1[reg];
    }
}

// =============== kernel 2: candidate top-k + exact refine + epilogue ===============
#define BLOCK 256
#define WAVES (BLOCK / 64)
#define MPT   (M_ALL / BLOCK)
#define WTOP  8                   // per-wave approx top-8
#define NCAND (WAVES * WTOP)      // 32 candidates
#define NREF  10                  // refine global approx top-10 exactly

__global__ __launch_bounds__(BLOCK) void gcn_topk(
    const float* __restrict__ logits,
    const float* __restrict__ micro,
    const float* __restrict__ label,
    const float* __restrict__ micro_all,
    const float* __restrict__ label_all,
    const float* __restrict__ fc_w,
    float* __restrict__ out,
    float* __restrict__ loss_arr)        // [N_Q] per-n loss, plain stores
{
    __shared__ float s_cv[NCAND];
    __shared__ int   s_ci[NCAND];
    __shared__ float s_ex[NREF];

    const int n    = blockIdx.x;
    const int t    = threadIdx.x;
    const int wave = t >> 6;
    const int lane = t & 63;

    // per-lane channel slice for exact recompute
    float4 b4 = *(const float4*)(micro + (size_t)n * CHN + lane * 4);
    float4 w4 = *(const float4*)(fc_w + lane * 4);
    w4.x -= INV_C; w4.y -= INV_C; w4.z -= INV_C; w4.w -= INV_C;

    float logit[MPT];
    #pragma unroll
    for (int j = 0; j < MPT; ++j)
        logit[j] = logits[(size_t)n * M_ALL + t + j * BLOCK];

    // ---- per-wave approx top-8 via shfl_xor butterflies ----
    unsigned taken = 0u;
    #pragma unroll
    for (int k = 0; k < WTOP; ++k) {
        float best  = -INFINITY;
        int   bestj = -1;
        #pragma unroll
        for (int j = 0; j < MPT; ++j) {
            bool avail = ((taken >> j) & 1u) == 0u;
            if (avail && logit[j] > best) { best = logit[j]; bestj = j; }
        }
        float v  = best;
        int   mi = (bestj < 0) ? -1 : (t + bestj * BLOCK);
        #pragma unroll
        for (int mask = 32; mask > 0; mask >>= 1) {
            float ov = __shfl_xor(v,  mask, 64);
            int   om = __shfl_xor(mi, mask, 64);
            if (ov > v) { v = ov; mi = om; }
        }
        if (lane == 0) {
            s_cv[wave * WTOP + k] = v;
            s_ci[wave * WTOP + k] = mi;
        }
        if (mi >= 0 && t == (mi & (BLOCK - 1))) taken |= 1u << (mi >> 8);
    }
    __syncthreads();

    // ---- global approx top-10 from 32 candidates (every thread, identical) ----
    float tv[NREF];
    int   ti[NREF];
    unsigned ctk = 0u;
    #pragma unroll
    for (int k = 0; k < NREF; ++k) {
        float best = -INFINITY;
        int   bi   = 0;
        #pragma unroll
        for (int c = 0; c < NCAND; ++c) {
            bool avail = ((ctk >> c) & 1u) == 0u;
            float cv = s_cv[c];
            if (avail && cv > best) { best = cv; bi = c; }
        }
        tv[k] = best;
        ti[k] = s_ci[bi];
        ctk |= 1u << bi;
    }

    // ---- exact fp32 recompute of the 10 candidate logits ----
    // logit_exact = sum_c w~_c * (a_mc - b_nc)^2   (matches reference formula)
    for (int c = wave; c < NREF; c += WAVES) {
        const int m = ti[c];
        const float4 a = *(const float4*)(micro_all + (size_t)m * CHN + lane * 4);
        const float dx = a.x - b4.x;
        const float dy = a.y - b4.y;
        const float dz = a.z - b4.z;
        const float dw = a.w - b4.w;
        float acc = dx * dx * w4.x + dy * dy * w4.y + dz * dz * w4.z + dw * dw * w4.w;
        #pragma unroll
        for (int mask = 32; mask >= 1; mask >>= 1)
            acc += __shfl_xor(acc, mask, 64);
        if (lane == 0) s_ex[c] = acc;
    }
    __syncthreads();

    // ---- exact top-6 of the 10 refined logits ----
    float top_val[TOPK];
    int   top_idx[TOPK];
    unsigned rtk = 0u;
    #pragma unroll
    for (int k = 0; k < TOPK; ++k) {
        float best = -INFINITY;
        int   bi   = 0;
        #pragma unroll
        for (int c = 0; c < NREF; ++c) {
            bool avail = ((rtk >> c) & 1u) == 0u;
            float cv = s_ex[c];
            if (avail && cv > best) { best = cv; bi = c; }
        }
        top_val[k] = best;
        top_idx[k] = ti[bi];
        rtk |= 1u << bi;
    }

    // ---- softmax over exact top-6 (full-softmax denom cancels in renorm) ----
    const float mx = top_val[0];
    float e[TOPK];
    float esum = 0.0f;
    #pragma unroll
    for (int k = 0; k < TOPK; ++k) { e[k] = __expf(top_val[k] - mx); esum += e[k]; }
    const float inv = 1.0f / esum;

    float outv = micro[(size_t)n * CHN + t];
    #pragma unroll
    for (int k = 0; k < TOPK; ++k)
        outv += (e[k] * inv) * micro_all[(size_t)top_idx[k] * CHN + t];
    out[n * CHN + t] = outv;

    if (t == 0) {
        const float lab = label[n];
        float l = 0.0f;
        #pragma unroll
        for (int k = 0; k < TOPK; ++k)
            l += (e[k] * inv) * fabsf(label_all[top_idx[k]] - lab);
        loss_arr[n] = l;          // plain store — no atomic
    }
}

// =============== kernel 3: reduce 512 per-n losses ===============
__global__ __launch_bounds__(256) void gcn_finalize(
    const float* __restrict__ loss_arr,
    float* __restrict__ out)
{
    __shared__ float red[4];
    const int t = threadIdx.x;
    float v = loss_arr[t] + loss_arr[t + 256];
    #pragma unroll
    for (int mask = 32; mask >= 1; mask >>= 1)
        v += __shfl_xor(v, mask, 64);
    if ((t & 63) == 0) red[t >> 6] = v;
    __syncthreads();
    if (t == 0)
        out[N_Q * CHN] = 1e-4f + (red[0] + red[1] + red[2] + red[3]) / (float)N_Q;
}

extern "C" void kernel_launch(void* const* d_in, const int* in_sizes, int n_in,
                              void* d_out, int out_size, void* d_ws, size_t ws_size,
                              hipStream_t stream) {
    const float* micro     = (const float*)d_in[0];
    const float* label     = (const float*)d_in[1];
    const float* micro_all = (const float*)d_in[2];
    const float* label_all = (const float*)d_in[3];
    const float* fc_w      = (const float*)d_in[4];
    float* out    = (float*)d_out;
    float* ws     = (float*)d_ws;
    float* loss   = ws + WS_LOSS;
    float* logits = ws + WS_LOGIT;

    gcn_gemm<<<dim3(M_ALL / BM, N_Q / BN), 256, 0, stream>>>(
        micro_all, micro, fc_w, logits);
    gcn_topk<<<N_Q, BLOCK, 0, stream>>>(logits, micro, label, micro_all,
                                        label_all, fc_w, out, loss);
    gcn_finalize<<<1, 256, 0, stream>>>(loss, out);
}